// Round 14
// baseline (117.359 us; speedup 1.0000x reference)
//
#include <hip/hip_runtime.h>

typedef __attribute__((ext_vector_type(8))) short short8;
typedef __attribute__((ext_vector_type(4))) float f32x4;
typedef __attribute__((ext_vector_type(2))) unsigned u32x2;

// fp32 -> bf16 round-to-nearest-even (single)
__device__ __forceinline__ unsigned short f2bf(float f) {
  unsigned u = __builtin_bit_cast(unsigned, f);
  u += 0x7fffu + ((u >> 16) & 1u);
  return (unsigned short)(u >> 16);
}
// fp32 pair -> packed bf16x2 via v_cvt_pk_bf16_f32 (no builtin on gfx950)
__device__ __forceinline__ unsigned pkbf(float a, float b) {
  unsigned r;
  asm("v_cvt_pk_bf16_f32 %0, %1, %2" : "=v"(r) : "v"(a), "v"(b));
  return r;
}

// ---------------------------------------------------------------------------
// prep: pure streaming, no barriers.
//  blocks [0,512):    per-(b,i) stats (m1b/m2b bf16, amv u16, meanb bf16),
//                     exact fp32 copy user -> out0 cols 0..127,
//                     userb = bf16(user).
//  blocks [512,800):  W1..W4 fp32 -> bf16 MFMA B-fragment swizzle.
//  blocks [800,928):  ris: exact fp32 copy -> out1 cols 0..127, risb bf16.
// ---------------------------------------------------------------------------
__global__ __launch_bounds__(256) void prep(
    const float* __restrict__ user, const float* __restrict__ ris,
    const float* __restrict__ W1, const float* __restrict__ W2,
    const float* __restrict__ W3, const float* __restrict__ W4,
    unsigned short* __restrict__ m1b, unsigned short* __restrict__ m2b,
    unsigned short* __restrict__ amv, unsigned short* __restrict__ meanb,
    unsigned short* __restrict__ risb, unsigned short* __restrict__ userb,
    unsigned short* __restrict__ W1f, unsigned short* __restrict__ W2f,
    unsigned short* __restrict__ W3f, unsigned short* __restrict__ W4f,
    float* __restrict__ out0, float* __restrict__ out1) {
  if (blockIdx.x < 512) {
    int idx = blockIdx.x * 256 + threadIdx.x;   // 0..131071 (B*IN)
    int b = idx >> 7, i = idx & 127;
    const float* up = user + (size_t)(b * 64) * 128 + i;
    float* op = out0 + (size_t)(b * 64) * 384 + i;
    unsigned short* ub = userb + (size_t)(b * 64) * 128 + i;
    float s = 0.f, m1 = -3.402823466e38f, m2 = -3.402823466e38f;
    int amx = 0;
    #pragma unroll 8
    for (int k = 0; k < 64; ++k) {
      float u = up[(size_t)k * 128];
      op[(size_t)k * 384] = u;                  // exact fp32 copy
      ub[(size_t)k * 128] = f2bf(u);            // bf16 for GEMM A
      s += u;
      if (u > m1) { m2 = m1; m1 = u; amx = k; }
      else if (u > m2) { m2 = u; }
    }
    m1b[idx] = f2bf(m1);
    m2b[idx] = f2bf(m2);
    amv[idx] = (unsigned short)amx;
    meanb[idx] = f2bf(s * (1.f / 64.f));
  } else if (blockIdx.x < 800) {
    int idx = ((blockIdx.x - 512) * 256 + threadIdx.x) * 4;  // 0..294908
    const float* src; unsigned short* dst; int kb; int rel;
    if (idx < 98304)        { src = W1; dst = W1f; kb = 12; rel = idx; }
    else if (idx < 163840)  { src = W2; dst = W2f; kb = 8;  rel = idx - 98304; }
    else if (idx < 229376)  { src = W3; dst = W3f; kb = 8;  rel = idx - 163840; }
    else                    { src = W4; dst = W4f; kb = 8;  rel = idx - 229376; }
    int kk = rel >> 8, n0 = rel & 255;
    f32x4 t = *(const f32x4*)(src + rel);
    #pragma unroll
    for (int j = 0; j < 4; ++j) {
      int n = n0 + j;
      int lane = (n & 15) | (((kk >> 3) & 3) << 4);
      int di = (((n >> 4) * kb + (kk >> 5)) * 64 + lane) * 8 + (kk & 7);
      dst[di] = f2bf(t[j]);
    }
  } else {
    int e = ((blockIdx.x - 800) * 256 + threadIdx.x) * 4;    // 0..131068
    f32x4 t = *(const f32x4*)(ris + e);
    int row = e >> 7, col = e & 127;
    *(f32x4*)(out1 + (size_t)row * 384 + col) = t;           // exact fp32 copy
    u32x2 p = { pkbf(t[0], t[1]), pkbf(t[2], t[3]) };
    *(u32x2*)(risb + e) = p;
  }
}

// ---------------------------------------------------------------------------
// gemm: ZERO barriers. 256 thr = 4 INDEPENDENT waves; each wave owns a
// private 16-row tile and a private 8 KiB LDS slice for the H transpose
// (same-wave write->read needs only lgkmcnt, no s_barrier).
// MODE 0 (blocks <1024): rows = (b,k); A = [userb | loo(stats) | risb bcast],
//   K=384, weights W1f/W2f, out = out0 cols 128..383.
// MODE 1 (blocks >=1024): rows = b; A = [risb | meanb], K=256, W3f/W4f, out1.
// ---------------------------------------------------------------------------
template<int MODE>
__device__ __forceinline__ void gemm_wave(
    int row0, unsigned short* __restrict__ Hw,
    const unsigned short* __restrict__ userb,
    const unsigned short* __restrict__ m1b, const unsigned short* __restrict__ m2b,
    const unsigned short* __restrict__ amv,
    const unsigned short* __restrict__ risb, const unsigned short* __restrict__ meanb,
    const unsigned short* __restrict__ Wa, const unsigned short* __restrict__ Wb,
    const float* __restrict__ ba, const float* __restrict__ bb,
    float* __restrict__ out) {
  constexpr int NFS = (MODE == 0) ? 12 : 8;
  const int lane = threadIdx.x & 63;
  const int r = lane & 15, g = lane >> 4;
  const int k8 = g * 8;
  const int b = row0 >> 6;           // batch (MODE 0)
  const int kb_ = row0 & 63;         // k-offset of this tile within its batch

  // ---- layer 1: acc[16] covers the full 16x256 H tile ----
  f32x4 acc[16];
  #pragma unroll
  for (int a = 0; a < 16; ++a) acc[a] = (f32x4)0.f;

  #pragma unroll
  for (int fs = 0; fs < NFS; ++fs) {
    short8 af;
    if constexpr (MODE == 0) {
      if (fs < 4) {
        af = *(const short8*)&userb[(size_t)(row0 + r) * 128 + fs * 32 + k8];
      } else if (fs < 8) {
        int c0 = b * 128 + (fs - 4) * 32 + k8;
        short8 m1v = *(const short8*)&m1b[c0];
        short8 m2v = *(const short8*)&m2b[c0];
        short8 amx = *(const short8*)&amv[c0];
        #pragma unroll
        for (int j = 0; j < 8; ++j)
          af[j] = ((unsigned short)amx[j] == (unsigned short)(kb_ + r)) ? m2v[j] : m1v[j];
      } else {
        af = *(const short8*)&risb[b * 128 + (fs - 8) * 32 + k8];  // row-bcast
      }
    } else {
      const unsigned short* src = (fs < 4) ? risb : meanb;
      af = *(const short8*)&src[(size_t)(row0 + r) * 128 + (fs & 3) * 32 + k8];
    }
    #pragma unroll
    for (int nfg = 0; nfg < 4; ++nfg) {
      short8 bf[4];
      #pragma unroll
      for (int q = 0; q < 4; ++q)
        bf[q] = *(const short8*)&Wa[(size_t)(((nfg * 4 + q) * NFS + fs) * 64 + lane) * 8];
      #pragma unroll
      for (int q = 0; q < 4; ++q)
        acc[nfg * 4 + q] = __builtin_amdgcn_mfma_f32_16x16x32_bf16(af, bf[q], acc[nfg * 4 + q], 0, 0, 0);
    }
  }

  // ---- H: bias+relu -> wave-private LDS (XOR-swizzled), no barrier ----
  #pragma unroll
  for (int nf = 0; nf < 16; ++nf) {
    float bav = ba[nf * 16 + r];
    #pragma unroll
    for (int j = 0; j < 4; ++j) {
      int rr = g * 4 + j;
      int col = nf * 16 + r;
      int cc = col >> 3;
      Hw[rr * 256 + ((cc ^ (rr & 7)) << 3) + (col & 7)] =
          f2bf(fmaxf(acc[nf][j] + bav, 0.f));
    }
  }

  // ---- layer 2: A from private LDS (lgkmcnt auto-inserted) ----
  f32x4 acc2[16];
  #pragma unroll
  for (int a = 0; a < 16; ++a) acc2[a] = (f32x4)0.f;
  #pragma unroll
  for (int kc = 0; kc < 8; ++kc) {
    int cc = kc * 4 + g;
    short8 af = *(const short8*)(Hw + r * 256 + ((cc ^ (r & 7)) << 3));
    #pragma unroll
    for (int nfg = 0; nfg < 4; ++nfg) {
      short8 bf[4];
      #pragma unroll
      for (int q = 0; q < 4; ++q)
        bf[q] = *(const short8*)&Wb[(size_t)(((nfg * 4 + q) * 8 + kc) * 64 + lane) * 8];
      #pragma unroll
      for (int q = 0; q < 4; ++q)
        acc2[nfg * 4 + q] = __builtin_amdgcn_mfma_f32_16x16x32_bf16(af, bf[q], acc2[nfg * 4 + q], 0, 0, 0);
    }
  }

  // ---- store out cols 128..383 ----
  #pragma unroll
  for (int nf = 0; nf < 16; ++nf) {
    float bbv = bb[nf * 16 + r];
    #pragma unroll
    for (int j = 0; j < 4; ++j) {
      int rr = g * 4 + j;
      out[(size_t)(row0 + rr) * 384 + 128 + nf * 16 + r] = acc2[nf][j] + bbv;
    }
  }
}

__global__ __launch_bounds__(256, 2) void gemm(
    const unsigned short* __restrict__ userb,
    const unsigned short* __restrict__ m1b, const unsigned short* __restrict__ m2b,
    const unsigned short* __restrict__ amv,
    const unsigned short* __restrict__ risb, const unsigned short* __restrict__ meanb,
    const unsigned short* __restrict__ W1f, const unsigned short* __restrict__ W2f,
    const unsigned short* __restrict__ W3f, const unsigned short* __restrict__ W4f,
    const float* __restrict__ b1, const float* __restrict__ b2,
    const float* __restrict__ b3, const float* __restrict__ b4,
    float* __restrict__ out0, float* __restrict__ out1) {
  __shared__ __align__(16) unsigned short Hs[4 * 16 * 256];  // 32 KiB, 8 KiB/wave
  const int wid = threadIdx.x >> 6;
  unsigned short* Hw = Hs + wid * 4096;
  if (blockIdx.x < 1024) {
    int row0 = (blockIdx.x * 4 + wid) * 16;
    gemm_wave<0>(row0, Hw, userb, m1b, m2b, amv, risb, meanb,
                 W1f, W2f, b1, b2, out0);
  } else {
    int row0 = ((blockIdx.x - 1024) * 4 + wid) * 16;
    gemm_wave<1>(row0, Hw, userb, m1b, m2b, amv, risb, meanb,
                 W3f, W4f, b3, b4, out1);
  }
}

// ---------------------------------------------------------------------------
extern "C" void kernel_launch(void* const* d_in, const int* in_sizes, int n_in,
                              void* d_out, int out_size, void* d_ws, size_t ws_size,
                              hipStream_t stream) {
  const float* user = (const float*)d_in[0];
  const float* ris  = (const float*)d_in[1];
  const float* W1 = (const float*)d_in[4];
  const float* b1 = (const float*)d_in[5];
  const float* W2 = (const float*)d_in[6];
  const float* b2 = (const float*)d_in[7];
  const float* W3 = (const float*)d_in[8];
  const float* b3 = (const float*)d_in[9];
  const float* W4 = (const float*)d_in[10];
  const float* b4 = (const float*)d_in[11];

  float* out0 = (float*)d_out;                         // (65536, 384)
  float* out1 = out0 + (size_t)65536 * 384;            // (1024, 384)

  char* ws = (char*)d_ws;
  unsigned short* meanb = (unsigned short*)(ws);             // 131072 bf16
  unsigned short* m1b   = (unsigned short*)(ws + 262144);
  unsigned short* m2b   = (unsigned short*)(ws + 524288);
  unsigned short* amvp  = (unsigned short*)(ws + 786432);    // u16 argmax
  unsigned short* risb  = (unsigned short*)(ws + 1048576);
  unsigned short* userb = (unsigned short*)(ws + 1310720);   // 16 MiB
  unsigned short* W1f   = (unsigned short*)(ws + 18087936);  // 192 KiB
  unsigned short* W2f   = (unsigned short*)(ws + 18284544);  // 128 KiB
  unsigned short* W3f   = (unsigned short*)(ws + 18415616);  // 128 KiB
  unsigned short* W4f   = (unsigned short*)(ws + 18546688);  // 128 KiB

  hipLaunchKernelGGL(prep, dim3(928), dim3(256), 0, stream,
                     user, ris, W1, W2, W3, W4,
                     m1b, m2b, amvp, meanb, risb, userb,
                     W1f, W2f, W3f, W4f, out0, out1);
  hipLaunchKernelGGL(gemm, dim3(1040), dim3(256), 0, stream,
                     userb, m1b, m2b, amvp, risb, meanb,
                     W1f, W2f, W3f, W4f, b1, b2, b3, b4, out0, out1);
}

// Round 15
// 81.994 us; speedup vs baseline: 1.4313x; 1.4313x over previous
//
#include <hip/hip_runtime.h>

typedef __attribute__((ext_vector_type(8))) short short8;
typedef __attribute__((ext_vector_type(4))) float f32x4;
typedef __attribute__((ext_vector_type(2))) unsigned u32x2;

// fp32 -> bf16 round-to-nearest-even (single)
__device__ __forceinline__ unsigned short f2bf(float f) {
  unsigned u = __builtin_bit_cast(unsigned, f);
  u += 0x7fffu + ((u >> 16) & 1u);
  return (unsigned short)(u >> 16);
}
__device__ __forceinline__ float bf2f(unsigned short u) {
  return __builtin_bit_cast(float, (unsigned)u << 16);
}
// fp32 pair -> packed bf16x2 via v_cvt_pk_bf16_f32 (no builtin on gfx950)
__device__ __forceinline__ unsigned pkbf(float a, float b) {
  unsigned r;
  asm("v_cvt_pk_bf16_f32 %0, %1, %2" : "=v"(r) : "v"(a), "v"(b));
  return r;
}

// ---------------------------------------------------------------------------
// wprep: W1..W4 fp32 -> bf16, MFMA B-fragment swizzle. 288 blocks x 256 thr.
// ---------------------------------------------------------------------------
__global__ __launch_bounds__(256) void wprep(
    const float* __restrict__ W1, const float* __restrict__ W2,
    const float* __restrict__ W3, const float* __restrict__ W4,
    unsigned short* __restrict__ W1f, unsigned short* __restrict__ W2f,
    unsigned short* __restrict__ W3f, unsigned short* __restrict__ W4f) {
  int idx = (blockIdx.x * 256 + threadIdx.x) * 4;  // 0..294908
  const float* src; unsigned short* dst; int kb; int rel;
  if (idx < 98304)        { src = W1; dst = W1f; kb = 12; rel = idx; }
  else if (idx < 163840)  { src = W2; dst = W2f; kb = 8;  rel = idx - 98304; }
  else if (idx < 229376)  { src = W3; dst = W3f; kb = 8;  rel = idx - 163840; }
  else                    { src = W4; dst = W4f; kb = 8;  rel = idx - 229376; }
  int kk = rel >> 8, n0 = rel & 255;
  f32x4 t = *(const f32x4*)(src + rel);
  #pragma unroll
  for (int j = 0; j < 4; ++j) {
    int n = n0 + j;
    int lane = (n & 15) | (((kk >> 3) & 3) << 4);
    int di = (((n >> 4) * kb + (kk >> 5)) * 64 + lane) * 8 + (kk & 7);
    dst[di] = f2bf(t[j]);
  }
}

// ---------------------------------------------------------------------------
// fusedU: TWO batches (128 rows) per block, 512 thr = 8 waves x 32-col slice.
// M-BLOCKING: per wave acc[8][2] -> 320 MFMA vs 40 weight loads (1:8 ratio;
// r7/r11 were 1:4). Loads per wave unchanged; barrier count halved chip-wide.
// LDS overlay: Hb 128x256 (64 KiB) aliases dead U 128x128 (32 KiB); +2 KiB
// stats => 67.6 KiB -> 2 blocks/CU. launch_bounds(512,1): no VGPR cap.
// ---------------------------------------------------------------------------
__global__ __launch_bounds__(512, 1) void fusedU(
    const float* __restrict__ user, const float* __restrict__ ris,
    const unsigned short* __restrict__ W1f, const unsigned short* __restrict__ W2f,
    const float* __restrict__ b1, const float* __restrict__ b2,
    float* __restrict__ out0, unsigned short* __restrict__ meanb) {
  // shorts [0,32768): Hb 128x256; first 16384 alias U 128x128.
  // shorts [32768,33792): m1s[2][128] | m2s[2][128] | ams[2][128] | risl[2][128]
  __shared__ __align__(16) unsigned short smem[33792];   // 67584 B
  unsigned short* const U    = smem;
  unsigned short* const Hb   = smem;
  unsigned short* const m1s  = smem + 32768;
  unsigned short* const m2s  = smem + 33024;
  unsigned short* const ams  = smem + 33280;
  unsigned short* const risl = smem + 33536;

  const int tid = threadIdx.x;
  const int bx = blockIdx.x;                  // 2 batches per block
  const size_t ubase = (size_t)bx * 16384;    // 128*128

  // ---- stage: 128x128 user tile -> out0 (exact fp32) + U (bf16 swizzled) ----
  #pragma unroll
  for (int it = 0; it < 8; ++it) {
    int e = it * 2048 + tid * 4;
    f32x4 t = *(const f32x4*)(user + ubase + e);
    int row = e >> 7, col = e & 127;
    *(f32x4*)(out0 + (size_t)(bx * 128 + row) * 384 + col) = t;
    u32x2 p = { pkbf(t[0], t[1]), pkbf(t[2], t[3]) };
    int cc = col >> 3, sub = col & 7;
    *(u32x2*)(U + row * 128 + ((cc ^ (row & 7)) << 3) + sub) = p;
  }
  if (tid < 256) risl[tid] = f2bf(ris[bx * 256 + tid]);
  __syncthreads();

  const int lane = tid & 63, wn = tid >> 6;   // 8 waves, 32-col slices
  const int r = lane & 15, g = lane >> 4;
  const int k8 = g * 8;
  const int j4 = g * 4;

  // ---- stats (waves 0-3): per (batch-half, column) over 64 rows ----
  float my_s = 0.f;
  if (tid < 256) {
    int bh = tid >> 7, c = tid & 127;
    int cc = c >> 3, sub = c & 7;
    float m1 = -3.402823466e38f, m2 = -3.402823466e38f;
    int amx = 0;
    #pragma unroll 8
    for (int row = 0; row < 64; ++row) {
      int gr = bh * 64 + row;
      float v = bf2f(U[gr * 128 + ((cc ^ (gr & 7)) << 3) + sub]);
      my_s += v;
      if (v > m1) { m2 = m1; m1 = v; amx = row; }
      else if (v > m2) { m2 = v; }
    }
    m1s[bh * 128 + c] = f2bf(m1);
    m2s[bh * 128 + c] = f2bf(m2);
    ams[bh * 128 + c] = (unsigned short)amx;
  }

  f32x4 acc[8][2];
  #pragma unroll
  for (int a = 0; a < 8; ++a) { acc[a][0] = (f32x4)0.f; acc[a][1] = (f32x4)0.f; }

  // ---- phase A: user chunks (fs 0..3), A from LDS, 16 MFMA per fs ----
  #pragma unroll
  for (int fs = 0; fs < 4; ++fs) {
    short8 w0 = *(const short8*)&W1f[(size_t)(((wn * 2 + 0) * 12 + fs) * 64 + lane) * 8];
    short8 w1 = *(const short8*)&W1f[(size_t)(((wn * 2 + 1) * 12 + fs) * 64 + lane) * 8];
    short8 af[8];
    #pragma unroll
    for (int mf = 0; mf < 8; ++mf) {
      int row = mf * 16 + r;
      int cc = fs * 4 + g;
      af[mf] = *(const short8*)(U + row * 128 + ((cc ^ (row & 7)) << 3));
    }
    #pragma unroll
    for (int mf = 0; mf < 8; ++mf) {
      acc[mf][0] = __builtin_amdgcn_mfma_f32_16x16x32_bf16(af[mf], w0, acc[mf][0], 0, 0, 0);
      acc[mf][1] = __builtin_amdgcn_mfma_f32_16x16x32_bf16(af[mf], w1, acc[mf][1], 0, 0, 0);
    }
  }

  // ---- phase B: RIS broadcast chunks (weights idx 8+fs) ----
  #pragma unroll
  for (int fs = 0; fs < 4; ++fs) {
    short8 w0 = *(const short8*)&W1f[(size_t)(((wn * 2 + 0) * 12 + 8 + fs) * 64 + lane) * 8];
    short8 w1 = *(const short8*)&W1f[(size_t)(((wn * 2 + 1) * 12 + 8 + fs) * 64 + lane) * 8];
    short8 v0 = *(const short8*)(risl + fs * 32 + k8);
    short8 v1 = *(const short8*)(risl + 128 + fs * 32 + k8);
    #pragma unroll
    for (int mf = 0; mf < 8; ++mf) {
      const short8 v = (mf < 4) ? v0 : v1;
      acc[mf][0] = __builtin_amdgcn_mfma_f32_16x16x32_bf16(v, w0, acc[mf][0], 0, 0, 0);
      acc[mf][1] = __builtin_amdgcn_mfma_f32_16x16x32_bf16(v, w1, acc[mf][1], 0, 0, 0);
    }
  }
  __syncthreads();   // stats visible; U dead after this point

  // ---- phase C: leave-one-out chunks (weights idx 4+fs) ----
  #pragma unroll
  for (int fs = 0; fs < 4; ++fs) {
    short8 w0 = *(const short8*)&W1f[(size_t)(((wn * 2 + 0) * 12 + 4 + fs) * 64 + lane) * 8];
    short8 w1 = *(const short8*)&W1f[(size_t)(((wn * 2 + 1) * 12 + 4 + fs) * 64 + lane) * 8];
    int c0 = fs * 32 + k8;
    short8 m1a = *(const short8*)(m1s + c0);
    short8 m2a = *(const short8*)(m2s + c0);
    short8 ama = *(const short8*)(ams + c0);
    short8 m1b_ = *(const short8*)(m1s + 128 + c0);
    short8 m2b_ = *(const short8*)(m2s + 128 + c0);
    short8 amb = *(const short8*)(ams + 128 + c0);
    #pragma unroll
    for (int mf = 0; mf < 8; ++mf) {
      int rk = (mf * 16 + r) & 63;   // row's k within its batch
      const short8 m1v = (mf < 4) ? m1a : m1b_;
      const short8 m2v = (mf < 4) ? m2a : m2b_;
      const short8 amv = (mf < 4) ? ama : amb;
      short8 t;
      #pragma unroll
      for (int j = 0; j < 8; ++j)
        t[j] = ((unsigned short)amv[j] == (unsigned short)rk) ? m2v[j] : m1v[j];
      acc[mf][0] = __builtin_amdgcn_mfma_f32_16x16x32_bf16(t, w0, acc[mf][0], 0, 0, 0);
      acc[mf][1] = __builtin_amdgcn_mfma_f32_16x16x32_bf16(t, w1, acc[mf][1], 0, 0, 0);
    }
  }

  // ---- H: bias + relu -> LDS (overwrites dead U) ----
  float ba[2] = { b1[wn * 32 + r], b1[wn * 32 + 16 + r] };
  #pragma unroll
  for (int mf = 0; mf < 8; ++mf)
    #pragma unroll
    for (int nf = 0; nf < 2; ++nf)
      #pragma unroll
      for (int j = 0; j < 4; ++j) {
        int rr = mf * 16 + j4 + j;
        int col = wn * 32 + nf * 16 + r;
        int cc = col >> 3;
        Hb[rr * 256 + ((cc ^ (rr & 7)) << 3) + (col & 7)] =
            f2bf(fmaxf(acc[mf][nf][j] + ba[nf], 0.f));
      }
  __syncthreads();

  // ---- layer 2: 128 rows x 32 cols per wave, A from LDS ----
  f32x4 acc2[8][2];
  #pragma unroll
  for (int a = 0; a < 8; ++a) { acc2[a][0] = (f32x4)0.f; acc2[a][1] = (f32x4)0.f; }
  #pragma unroll
  for (int kc = 0; kc < 8; ++kc) {
    short8 w0 = *(const short8*)&W2f[(size_t)(((wn * 2 + 0) * 8 + kc) * 64 + lane) * 8];
    short8 w1 = *(const short8*)&W2f[(size_t)(((wn * 2 + 1) * 8 + kc) * 64 + lane) * 8];
    short8 af[8];
    #pragma unroll
    for (int mf = 0; mf < 8; ++mf) {
      int rr = mf * 16 + r;
      int cc = kc * 4 + g;
      af[mf] = *(const short8*)(Hb + rr * 256 + ((cc ^ (rr & 7)) << 3));
    }
    #pragma unroll
    for (int mf = 0; mf < 8; ++mf) {
      acc2[mf][0] = __builtin_amdgcn_mfma_f32_16x16x32_bf16(af[mf], w0, acc2[mf][0], 0, 0, 0);
      acc2[mf][1] = __builtin_amdgcn_mfma_f32_16x16x32_bf16(af[mf], w1, acc2[mf][1], 0, 0, 0);
    }
  }

  // ---- store out0 cols 128..383 ----
  float bb[2] = { b2[wn * 32 + r], b2[wn * 32 + 16 + r] };
  #pragma unroll
  for (int mf = 0; mf < 8; ++mf)
    #pragma unroll
    for (int nf = 0; nf < 2; ++nf)
      #pragma unroll
      for (int j = 0; j < 4; ++j) {
        int rr = mf * 16 + j4 + j;
        int col = wn * 32 + nf * 16 + r;
        out0[(size_t)(bx * 128 + rr) * 384 + 128 + col] = acc2[mf][nf][j] + bb[nf];
      }

  // ---- meanb (2 batches) at kernel end ----
  if (tid < 256) meanb[bx * 256 + tid] = f2bf(my_s * (1.f / 64.f));
}

// ---------------------------------------------------------------------------
// fusedR: RIS path. 16 blocks x 512 thr.
// A = [ris (fp32->bf16 in-reg) | meanb]; also writes out1 cols 0..127 fp32.
// ---------------------------------------------------------------------------
__global__ __launch_bounds__(512, 4) void fusedR(
    const float* __restrict__ ris, const unsigned short* __restrict__ meanb,
    const unsigned short* __restrict__ W3f, const unsigned short* __restrict__ W4f,
    const float* __restrict__ b3, const float* __restrict__ b4,
    float* __restrict__ out1) {
  __shared__ unsigned short Hb[64 * 256];   // 32 KiB, XOR-swizzled

  const int tid = threadIdx.x;
  const int row0 = blockIdx.x * 64;

  #pragma unroll
  for (int it = 0; it < 4; ++it) {
    int e = it * 2048 + tid * 4;
    f32x4 t = *(const f32x4*)(ris + (size_t)row0 * 128 + e);
    int row = e >> 7, col = e & 127;
    *(f32x4*)(out1 + (size_t)(row0 + row) * 384 + col) = t;
  }

  const int lane = tid & 63, wn = tid >> 6;
  const int r = lane & 15;
  const int k8 = (lane >> 4) * 8;
  const int j4 = (lane >> 4) * 4;

  f32x4 acc[4][2];
  #pragma unroll
  for (int a = 0; a < 4; ++a) { acc[a][0] = (f32x4)0.f; acc[a][1] = (f32x4)0.f; }

  #pragma unroll
  for (int fs = 0; fs < 8; ++fs) {
    short8 af[4];
    if (fs < 4) {
      #pragma unroll
      for (int mf = 0; mf < 4; ++mf) {
        const float* p = &ris[(size_t)(row0 + mf * 16 + r) * 128 + fs * 32 + k8];
        f32x4 t0 = *(const f32x4*)p;
        f32x4 t1 = *(const f32x4*)(p + 4);
        short8 t;
        #pragma unroll
        for (int j = 0; j < 4; ++j) { t[j] = (short)f2bf(t0[j]); t[4 + j] = (short)f2bf(t1[j]); }
        af[mf] = t;
      }
    } else {
      #pragma unroll
      for (int mf = 0; mf < 4; ++mf)
        af[mf] = *(const short8*)&meanb[(size_t)(row0 + mf * 16 + r) * 128 + (fs - 4) * 32 + k8];
    }
    short8 w0 = *(const short8*)&W3f[(size_t)(((wn * 2 + 0) * 8 + fs) * 64 + lane) * 8];
    short8 w1 = *(const short8*)&W3f[(size_t)(((wn * 2 + 1) * 8 + fs) * 64 + lane) * 8];
    #pragma unroll
    for (int mf = 0; mf < 4; ++mf) {
      acc[mf][0] = __builtin_amdgcn_mfma_f32_16x16x32_bf16(af[mf], w0, acc[mf][0], 0, 0, 0);
      acc[mf][1] = __builtin_amdgcn_mfma_f32_16x16x32_bf16(af[mf], w1, acc[mf][1], 0, 0, 0);
    }
  }

  float ba[2] = { b3[wn * 32 + r], b3[wn * 32 + 16 + r] };
  #pragma unroll
  for (int mf = 0; mf < 4; ++mf)
    #pragma unroll
    for (int nf = 0; nf < 2; ++nf)
      #pragma unroll
      for (int j = 0; j < 4; ++j) {
        int rr = mf * 16 + j4 + j;
        int col = wn * 32 + nf * 16 + r;
        int cc = col >> 3;
        Hb[rr * 256 + ((cc ^ (rr & 7)) << 3) + (col & 7)] =
            f2bf(fmaxf(acc[mf][nf][j] + ba[nf], 0.f));
      }
  __syncthreads();

  f32x4 acc2[4][2];
  #pragma unroll
  for (int a = 0; a < 4; ++a) { acc2[a][0] = (f32x4)0.f; acc2[a][1] = (f32x4)0.f; }
  #pragma unroll
  for (int kc = 0; kc < 8; ++kc) {
    short8 af[4];
    #pragma unroll
    for (int mf = 0; mf < 4; ++mf) {
      int rr = mf * 16 + r;
      int cc = kc * 4 + (lane >> 4);
      af[mf] = *(const short8*)(Hb + rr * 256 + ((cc ^ (rr & 7)) << 3));
    }
    short8 w0 = *(const short8*)&W4f[(size_t)(((wn * 2 + 0) * 8 + kc) * 64 + lane) * 8];
    short8 w1 = *(const short8*)&W4f[(size_t)(((wn * 2 + 1) * 8 + kc) * 64 + lane) * 8];
    #pragma unroll
    for (int mf = 0; mf < 4; ++mf) {
      acc2[mf][0] = __builtin_amdgcn_mfma_f32_16x16x32_bf16(af[mf], w0, acc2[mf][0], 0, 0, 0);
      acc2[mf][1] = __builtin_amdgcn_mfma_f32_16x16x32_bf16(af[mf], w1, acc2[mf][1], 0, 0, 0);
    }
  }

  float bb[2] = { b4[wn * 32 + r], b4[wn * 32 + 16 + r] };
  #pragma unroll
  for (int mf = 0; mf < 4; ++mf)
    #pragma unroll
    for (int nf = 0; nf < 2; ++nf)
      #pragma unroll
      for (int j = 0; j < 4; ++j) {
        int rr = mf * 16 + j4 + j;
        int col = wn * 32 + nf * 16 + r;
        out1[(size_t)(row0 + rr) * 384 + 128 + col] = acc2[mf][nf][j] + bb[nf];
      }
}

// ---------------------------------------------------------------------------
extern "C" void kernel_launch(void* const* d_in, const int* in_sizes, int n_in,
                              void* d_out, int out_size, void* d_ws, size_t ws_size,
                              hipStream_t stream) {
  const float* user = (const float*)d_in[0];
  const float* ris  = (const float*)d_in[1];
  const float* W1 = (const float*)d_in[4];
  const float* b1 = (const float*)d_in[5];
  const float* W2 = (const float*)d_in[6];
  const float* b2 = (const float*)d_in[7];
  const float* W3 = (const float*)d_in[8];
  const float* b3 = (const float*)d_in[9];
  const float* W4 = (const float*)d_in[10];
  const float* b4 = (const float*)d_in[11];

  float* out0 = (float*)d_out;                         // (65536, 384)
  float* out1 = out0 + (size_t)65536 * 384;            // (1024, 384)

  char* ws = (char*)d_ws;
  unsigned short* meanb = (unsigned short*)(ws);            // 131072 bf16
  unsigned short* W1f   = (unsigned short*)(ws + 262144);   // 98304 bf16
  unsigned short* W2f   = (unsigned short*)(ws + 458752);   // 65536 bf16
  unsigned short* W3f   = (unsigned short*)(ws + 589824);   // 65536 bf16
  unsigned short* W4f   = (unsigned short*)(ws + 720896);   // 65536 bf16

  hipLaunchKernelGGL(wprep, dim3(288), dim3(256), 0, stream,
                     W1, W2, W3, W4, W1f, W2f, W3f, W4f);
  hipLaunchKernelGGL(fusedU, dim3(512), dim3(512), 0, stream,
                     user, ris, W1f, W2f, b1, b2, out0, meanb);
  hipLaunchKernelGGL(fusedR, dim3(16), dim3(512), 0, stream,
                     ris, meanb, W3f, W4f, b3, b4, out1);
}